// Round 4
// baseline (123.615 us; speedup 1.0000x reference)
//
#include <hip/hip_runtime.h>
#include <hip/hip_bf16.h>

#define N 8192
#define D 256
#define NC 64
// sim = dot/0.5 = 2*dot; rows normalized -> fixed shift 2.0 replaces row-max
// (log-sum-exp shift invariance). Positive-pair sum handled analytically:
//   sum_pos s_ij = 2*(sum_c ||S_c||^2 - N),  S_c = sum_{lab=c} e_i  (fp32 exact)
// so the O(N^2) kernel computes ONLY Z_i = sum_j exp(s_ij - 2).

typedef __attribute__((ext_vector_type(8))) short bf16x8;
typedef __attribute__((ext_vector_type(4))) float f32x4;

#define BM 256        // rows per block (4 waves x 64)
#define CT 64         // cols per tile
#define NTILE 8       // tiles per block -> 512 cols per block
#define GRID 512      // 32 row panels x 16 col chunks (2 blocks/CU, single pass)

#define K1 2.8853900817779268f   // 2*log2(e)
#define K2 (-2.8853900817779268f)

__device__ inline unsigned short f2bf(float x) {
    __hip_bfloat16 h = __float2bfloat16(x);
    return *reinterpret_cast<unsigned short*>(&h);
}

__device__ inline float fast_exp2(float t) {
#if __has_builtin(__builtin_amdgcn_exp2f)
    return __builtin_amdgcn_exp2f(t);
#else
    return __expf(t * 0.69314718056f);
#endif
}

// ---------------- kernel 1: fp32 -> bf16 convert + zero Z and S ----------------
__global__ void convert_kernel(const float4* __restrict__ E4, ushort4* __restrict__ Ebf4,
                               float* __restrict__ Z, float* __restrict__ S) {
    int i = blockIdx.x * blockDim.x + threadIdx.x;
    if (i < (N * D) / 4) {
        float4 v = E4[i];
        ushort4 o;
        o.x = f2bf(v.x); o.y = f2bf(v.y); o.z = f2bf(v.z); o.w = f2bf(v.w);
        Ebf4[i] = o;
    }
    if (i < N) Z[i] = 0.0f;
    if (i < NC * D) S[i] = 0.0f;
}

// ---------------- kernel 2: class sums S_c = sum_{lab_i=c} e_i (fp32) ----------------
__global__ __launch_bounds__(256)
void classsum_kernel(const float* __restrict__ emb, const int* __restrict__ labels,
                     float* __restrict__ S) {
    __shared__ float Sl[NC * D];   // 64 KB
    int t = threadIdx.x;
    for (int i = t; i < NC * D; i += 256) Sl[i] = 0.0f;
    __syncthreads();
    int rbase = blockIdx.x * 64;   // 128 blocks x 64 rows
    for (int r = 0; r < 64; ++r) {
        int i = rbase + r;
        int lab = labels[i];       // uniform -> scalar load
        Sl[lab * D + t] += emb[(size_t)i * D + t];
    }
    __syncthreads();
    for (int i = t; i < NC * D; i += 256) atomicAdd(&S[i], Sl[i]);
}

// ---------------- kernel 3: Z-only fused sim + exp-sum ----------------
// 512 blocks x 256 thr (4 waves). Block: rows [r0,r0+256) x cols [c0,c0+512).
// Wave w owns 64 rows (rg=4 x 16): A-frags fully register-resident (128 VGPR),
// each B ds_read feeds 4 MFMAs. B tile 64 cols x 256 k (32 KB) double-buffered,
// staged via global_load_lds(16B) with linear LDS dest + inverse-swizzled global
// source (rule #21); swizzle confined to 16B-seg bits -> zero conflicts (r2-verified).
__global__ __launch_bounds__(256, 2)
void sim_kernel(const __hip_bfloat16* __restrict__ Ebf, float* __restrict__ Z) {
    __shared__ unsigned char Bsh[2 * 32768];   // 64 KB

    const int tid  = threadIdx.x;
    const int lane = tid & 63;
    const int w    = tid >> 6;
    const int r0   = (blockIdx.x >> 4) * BM;
    const int c0   = (blockIdx.x & 15) * (CT * NTILE);
    const char* eb = (const char*)Ebf;

    // A fragments: row = lane&15, k-seg = lane>>4; 4 row-groups x 8 kg x 16B
    bf16x8 a[4][8];
#pragma unroll
    for (int rg = 0; rg < 4; ++rg) {
        int row = r0 + w * 64 + rg * 16 + (lane & 15);
        const char* rp = eb + (size_t)row * 512 + ((lane >> 4) * 16);
#pragma unroll
        for (int kg = 0; kg < 8; ++kg)
            a[rg][kg] = *reinterpret_cast<const bf16x8*>(rp + kg * 64);
    }

    float zacc[4][4];
#pragma unroll
    for (int rg = 0; rg < 4; ++rg)
#pragma unroll
        for (int r = 0; r < 4; ++r) zacc[rg][r] = 0.0f;

    // staging source base: chunk c = w*8+m -> kg=c>>2, colblk=c&3;
    // colLocal = colblk*16 + (lane>>2); seg swizzle reduces to lane-only:
    // seg = (lane&3) ^ ((lane>>3)&3)  (since colblk*8 % 4 == 0)
    const int seg = (lane & 3) ^ ((lane >> 3) & 3);
    const char* sbase = eb + (size_t)(c0 + (lane >> 2)) * 512 + seg * 16;

    // swizzled ds_read base (col = cg*16 + (lane&15); cg*8 % 4 == 0):
    const unsigned rb0 =
        (unsigned)((lane & 15) * 64 +
                   (((lane >> 4) ^ (((lane & 15) >> 1) & 3)) << 4));

    auto stage = [&](int buf, int t) {
#pragma unroll
        for (int m = 0; m < 8; ++m) {
            int c = w * 8 + m;
            int kg = c >> 2, colblk = c & 3;
            __builtin_amdgcn_global_load_lds(
                (const __attribute__((address_space(1))) void*)
                    (sbase + (size_t)t * (CT * 512) + colblk * 8192 + kg * 64),
                (__attribute__((address_space(3))) void*)
                    (Bsh + buf * 32768 + kg * 4096 + colblk * 1024),
                16, 0, 0);
        }
    };

    auto do_tile = [&](int t, int buf) {
        if (t + 1 < NTILE) stage(buf ^ 1, t + 1);

        f32x4 acc[4][4];
#pragma unroll
        for (int rg = 0; rg < 4; ++rg)
#pragma unroll
            for (int cg = 0; cg < 4; ++cg) acc[rg][cg] = (f32x4){0.f, 0.f, 0.f, 0.f};

#pragma unroll
        for (int kg = 0; kg < 8; ++kg) {
            bf16x8 b[4];
#pragma unroll
            for (int cg = 0; cg < 4; ++cg)
                b[cg] = *reinterpret_cast<const bf16x8*>(
                    Bsh + buf * 32768 + kg * 4096 + cg * 1024 + rb0);
#pragma unroll
            for (int rg = 0; rg < 4; ++rg)
#pragma unroll
                for (int cg = 0; cg < 4; ++cg)
                    acc[rg][cg] = __builtin_amdgcn_mfma_f32_16x16x32_bf16(
                        a[rg][kg], b[cg], acc[rg][cg], 0, 0, 0);
        }

        // epilogue: Z partial = sum exp2(K1*dot + K2)  (= exp(2*dot - 2))
#pragma unroll
        for (int rg = 0; rg < 4; ++rg)
#pragma unroll
            for (int r = 0; r < 4; ++r) {
                float s = zacc[rg][r];
#pragma unroll
                for (int cg = 0; cg < 4; ++cg)
                    s += fast_exp2(__builtin_fmaf(acc[rg][cg][r], K1, K2));
                zacc[rg][r] = s;
            }

        __syncthreads();   // drains vmcnt: next tile staged; buf readers done
    };

    stage(0, 0);
    __syncthreads();
    for (int t = 0; t < NTILE; t += 2) {
        do_tile(t, 0);
        do_tile(t + 1, 1);
    }

    // 16-lane shfl reduce (cols) then one atomic per row
#pragma unroll
    for (int rg = 0; rg < 4; ++rg)
#pragma unroll
        for (int r = 0; r < 4; ++r) {
            float z = zacc[rg][r];
#pragma unroll
            for (int m = 1; m <= 8; m <<= 1) z += __shfl_xor(z, m, 64);
            if ((lane & 15) == 0) {
                int row = r0 + w * 64 + rg * 16 + (lane >> 4) * 4 + r;
                atomicAdd(&Z[row], z);
            }
        }
}

// ---------------- kernel 4: finalize ----------------
// num = sum_i c_i*(2 + ln(Z_i - 1)) - 2*(sum_c ||S_c||^2 - N);  den = sum_i c_i
__global__ __launch_bounds__(1024)
void finalize_kernel(const float* __restrict__ Z, const float* __restrict__ S,
                     const int* __restrict__ labels, float* __restrict__ out) {
    __shared__ int hist[NC];
    __shared__ float s0[1024], s1[1024];
    int t = threadIdx.x;
    if (t < NC) hist[t] = 0;
    __syncthreads();
    for (int i = t; i < N; i += 1024) atomicAdd(&hist[labels[i]], 1);
    __syncthreads();

    float num = 0.0f, den = 0.0f;
    for (int i = t; i < N; i += 1024) {
        float z = Z[i] - 1.0f;                 // remove diag exp(s_ii-2) ~= 1
        float c = (float)(hist[labels[i]] - 1);
        num += c * (2.0f + __logf(z));
        den += c;
    }
    float ss = 0.0f;
    for (int i = t; i < NC * D; i += 1024) { float v = S[i]; ss += v * v; }
    num -= 2.0f * ss / 1.0f;   // subtract 2*sum||S_c||^2 (add back 2N below)

    s0[t] = num; s1[t] = den;
    __syncthreads();
    for (int s = 512; s > 0; s >>= 1) {
        if (t < s) { s0[t] += s0[t + s]; s1[t] += s1[t + s]; }
        __syncthreads();
    }
    if (t == 0) out[0] = (s0[0] + 2.0f * (float)N) / s1[0];
}

extern "C" void kernel_launch(void* const* d_in, const int* in_sizes, int n_in,
                              void* d_out, int out_size, void* d_ws, size_t ws_size,
                              hipStream_t stream) {
    const float* emb  = (const float*)d_in[0];
    const int* labels = (const int*)d_in[1];
    float* out = (float*)d_out;

    char* ws = (char*)d_ws;
    __hip_bfloat16* Ebf = (__hip_bfloat16*)ws;          // 4 MB
    float* Z = (float*)(ws + (size_t)N * D * 2);        // 32 KB
    float* S = Z + N;                                   // 64 KB (64x256 fp32)

    convert_kernel<<<(N * D / 4 + 255) / 256, 256, 0, stream>>>(
        (const float4*)emb, (ushort4*)Ebf, Z, S);
    classsum_kernel<<<N / 64, 256, 0, stream>>>(emb, labels, S);
    sim_kernel<<<GRID, 256, 0, stream>>>(Ebf, Z);
    finalize_kernel<<<1, 1024, 0, stream>>>(Z, S, labels, out);
}